// Round 7
// baseline (37.396 us; speedup 1.0000x reference)
//
#include <hip/hip_runtime.h>
#include <math.h>

#ifndef M_PI
#define M_PI 3.14159265358979323846
#endif

#define DEG 16
#define NPB 16                  // nodes per tile
#define THREADS (DEG * NPB)     // 256
#define TILES_PER_BLOCK 2

// Single fused kernel. One lane per edge; 16 lanes per node-group (groups are
// wave-internal -> no per-tile barriers needed; compiler lgkmcnt ordering
// suffices, verified R6 absmax=0). Each block sweeps TILES_PER_BLOCK tiles
// grid-stride, accumulating per-lane energy in registers; ONE device-scope
// atomicAdd per block into d_out (R3 lesson: no per-block __threadfence;
// atomicAdd is device-scope by default). d_out is zeroed by a memset node.
// Zeta body is R5's proven-fastest form: 3 staged float4 per active edge,
// order-preserving per-16-group compaction (bit-matches reference order).
__global__ __launch_bounds__(THREADS) void tersoff_fused(
    const float* __restrict__ pos,
    const float* __restrict__ log_A,  const float* __restrict__ log_B,
    const float* __restrict__ log_l1, const float* __restrict__ log_l2,
    const float* __restrict__ log_l3, const float* __restrict__ log_beta,
    const float* __restrict__ log_n,  const float* __restrict__ log_gamma,
    const float* __restrict__ log_c,  const float* __restrict__ log_d,
    const float* __restrict__ E_ref,  const float* __restrict__ h_vals,
    const float* __restrict__ R_cut,  const float* __restrict__ D_wid,
    const int*  __restrict__ edge_dst,
    const int*  __restrict__ atom_types,
    const int*  __restrict__ imap,
    float* __restrict__ out, int nAtoms, int nTiles)
{
    __shared__ float PT[3][16];
    __shared__ int   IM[4];
    __shared__ float ER[2];
    // [node][slot][3 float4]; slot dim padded to 17 -> node stride 51 float4:
    // 4 node-groups of a wave hit disjoint bank quads; within a group all
    // lanes read the same slot (broadcast, conflict-free).
    __shared__ float4 ED[NPB][DEG + 1][3];
    __shared__ float WS[THREADS / 64];

    if (threadIdx.x < 3) {
        int t = threadIdx.x;
        float A  = expf(log_A[t]);   float B  = expf(log_B[t]);
        float l1 = expf(log_l1[t]);  float l2 = expf(log_l2[t]);
        float l3 = expf(log_l3[t]);  float be = expf(log_beta[t]);
        float nn = expf(log_n[t]);   float ga = expf(log_gamma[t]);
        float c  = expf(log_c[t]);   float d  = expf(log_d[t]);
        float c2 = c * c, d2 = d * d;
        float R  = R_cut[t], D = D_wid[t];
        PT[t][0] = A;   PT[t][1] = B;
        PT[t][2] = l1;  PT[t][3] = l2;
        PT[t][4] = l3;  PT[t][5] = be;
        PT[t][6] = nn;  PT[t][7] = -1.0f / (2.0f * nn);
        PT[t][8] = h_vals[t];
        PT[t][9] = ga * (1.0f + c2 / d2);   // g1
        PT[t][10] = ga * c2;                // gc2
        PT[t][11] = d2;
        PT[t][12] = R - D;
        PT[t][13] = R + D;
        PT[t][14] = (float)M_PI / (2.0f * D);
    }
    if (threadIdx.x >= 64 && threadIdx.x < 68) IM[threadIdx.x - 64] = imap[threadIdx.x - 64];
    if (threadIdx.x >= 68 && threadIdx.x < 70) ER[threadIdx.x - 68] = E_ref[threadIdx.x - 68];
    __syncthreads();

    int nl   = threadIdx.x >> 4;          // node slot in tile (wave-local)
    int e    = threadIdx.x & (DEG - 1);   // edge slot within node
    int lane = threadIdx.x & 63;

    float acc = 0.0f;

    for (int tile = blockIdx.x; tile < nTiles; tile += gridDim.x) {
        int node = tile * NPB + nl;
        bool valid = (node < nAtoms);
        int nc = valid ? node : 0;

        int dst = edge_dst[nc * DEG + e];
        int ti  = atom_types[nc];
        int tj  = atom_types[dst];
        int p   = IM[ti * 2 + tj];

        float vx = pos[3 * dst]     - pos[3 * nc];
        float vy = pos[3 * dst + 1] - pos[3 * nc + 1];
        float vz = pos[3 * dst + 2] - pos[3 * nc + 2];
        float r2 = vx * vx + vy * vy + vz * vz;
        float inv_r = __builtin_amdgcn_rsqf(r2);
        float r = r2 * inv_r;

        float RmD = PT[p][12], RpD = PT[p][13], piD = PT[p][14];
        float fc;
        if (r < RmD)      fc = 1.0f;
        else if (r < RpD) fc = 0.5f - 0.5f * __sinf(piD * (r - RmD));
        else              fc = 0.0f;
        if (!valid) fc = 0.0f;

        float h  = PT[p][8], g1 = PT[p][9], gc2 = PT[p][10], d2 = PT[p][11];
        float ux = vx * inv_r, uy = vy * inv_r, uz = vz * inv_r;

        // order-preserving per-16-group compaction of active edges
        unsigned long long bal = __ballot(fc > 0.0f);
        unsigned gm  = (unsigned)((bal >> (lane & 48)) & 0xFFFFull);
        int nact = __popc(gm);
        int rank = __popc(gm & ((1u << (lane & 15)) - 1u));
        if (fc > 0.0f) {
            ED[nl][rank][0] = make_float4(ux, uy, uz, r);
            ED[nl][rank][1] = make_float4(fc, PT[p][4], h, g1);
            ED[nl][rank][2] = make_float4(gc2, d2, 0.0f, 0.0f);
        }
        if (valid && e == 0) acc += ti ? ER[1] : ER[0];

        if (fc > 0.0f) {
            float zeta = 0.0f;
            for (int s = 0; s < nact; ++s) {
                if (s == rank) continue;       // skip self
                float4 fa = ED[nl][s][0];      // {ux, uy, uz, r}
                float4 fb = ED[nl][s][1];      // {fc, lam3, h, g1}
                float4 fx = ED[nl][s][2];      // {gc2, d2, -, -}
                float ct = ux * fa.x + uy * fa.y + uz * fa.z;
                ct = fminf(fmaxf(ct, -1.0f), 1.0f);
                bool mine = (s < rank);        // ang params from larger-index edge
                float hh  = mine ? h   : fb.z;
                float G1  = mine ? g1  : fb.w;
                float GC2 = mine ? gc2 : fx.x;
                float D2  = mine ? d2  : fx.y;
                float hm  = hh - ct;
                float ang = G1 - GC2 * __builtin_amdgcn_rcpf(D2 + hm * hm);
                float ex  = __expf(fminf(fb.y * (r - fa.w), 35.0f));
                zeta += fb.x * ang * ex;
            }
            float be  = PT[p][5], nn = PT[p][6], m2n = PT[p][7];
            float xx  = __powf(be * zeta, nn);     // (beta*zeta)^n
            float bo  = __powf(1.0f + xx, m2n);    // (1+x)^(-1/(2n))
            float rep =  PT[p][0] * __expf(-PT[p][2] * r);
            float att = -PT[p][1] * __expf(-PT[p][3] * r);
            acc += 0.5f * fc * (rep + bo * att);
        }
        // no per-tile barrier: ED sharing is wave-internal (R6: verified)
    }

    // once per block: wave reduce, cross-wave via LDS, one atomic per block
    for (int o = 32; o > 0; o >>= 1) acc += __shfl_down(acc, o, 64);
    if ((threadIdx.x & 63) == 0) WS[threadIdx.x >> 6] = acc;
    __syncthreads();
    if (threadIdx.x == 0) {
        float s = 0.0f;
        #pragma unroll
        for (int w = 0; w < THREADS / 64; ++w) s += WS[w];
        atomicAdd(out, s);    // device-scope by default (m20); 1563 total
    }
}

extern "C" void kernel_launch(void* const* d_in, const int* in_sizes, int n_in,
                              void* d_out, int out_size, void* d_ws, size_t ws_size,
                              hipStream_t stream) {
    const float* pos      = (const float*)d_in[0];
    const float* log_A    = (const float*)d_in[1];
    const float* log_B    = (const float*)d_in[2];
    const float* log_l1   = (const float*)d_in[3];
    const float* log_l2   = (const float*)d_in[4];
    const float* log_l3   = (const float*)d_in[5];
    const float* log_beta = (const float*)d_in[6];
    const float* log_n    = (const float*)d_in[7];
    const float* log_gam  = (const float*)d_in[8];
    const float* log_c    = (const float*)d_in[9];
    const float* log_d    = (const float*)d_in[10];
    const float* E_ref    = (const float*)d_in[11];
    const float* h_vals   = (const float*)d_in[12];
    const float* R_cut    = (const float*)d_in[13];
    const float* D_wid    = (const float*)d_in[14];
    const int*   edge_idx = (const int*)d_in[15];
    // d_in[16] trip_ij, d_in[17] trip_ik: implicit (triu pairs per node) -- unused.
    const int*   atypes   = (const int*)d_in[18];
    const int*   imap     = (const int*)d_in[19];
    // d_in[20] batch: all zeros -- unused.

    int nAtoms = in_sizes[0] / 3;
    int E      = in_sizes[15] / 2;
    const int* edge_dst = edge_idx + E;

    int nTiles = (nAtoms + NPB - 1) / NPB;                          // 3125
    int grid   = (nTiles + TILES_PER_BLOCK - 1) / TILES_PER_BLOCK;  // 1563

    // zero the accumulator (replays must not inherit previous sums)
    hipMemsetAsync(d_out, 0, sizeof(float), stream);

    tersoff_fused<<<grid, THREADS, 0, stream>>>(
        pos, log_A, log_B, log_l1, log_l2, log_l3, log_beta, log_n,
        log_gam, log_c, log_d, E_ref, h_vals, R_cut, D_wid,
        edge_dst, atypes, imap, (float*)d_out, nAtoms, nTiles);
}

// Round 8
// 31.201 us; speedup vs baseline: 1.1986x; 1.1986x over previous
//
#include <hip/hip_runtime.h>
#include <math.h>

#ifndef M_PI
#define M_PI 3.14159265358979323846
#endif

#define DEG 16
#define NPB 16                  // nodes per tile
#define THREADS (DEG * NPB)     // 256

// ---------------------------------------------------------------------------
// Pack: pos4[i] = {x, y, z, bitcast(atom_type)} so main's per-edge gather is
// ONE global_load_dwordx4 instead of 4 address-divergent instructions.
// ---------------------------------------------------------------------------
__global__ __launch_bounds__(256) void pack_kernel(
    const float* __restrict__ pos, const int* __restrict__ atom_types,
    float4* __restrict__ pos4, int nAtoms)
{
    for (int i = blockIdx.x * 256 + threadIdx.x; i < nAtoms; i += gridDim.x * 256)
        pos4[i] = make_float4(pos[3 * i], pos[3 * i + 1], pos[3 * i + 2],
                              __int_as_float(atom_types[i]));
}

// ---------------------------------------------------------------------------
// Main: one lane per edge; 16 lanes per node-group; 16 nodes per tile; each
// block processes 2 tiles with BOTH tiles' global loads prefetched up front
// (tile 1's dependent-load chain overlaps tile 0's compute). Per-tile
// __syncthreads kept deliberately (R6/R7: removing them regressed — lockstep
// waves share warm L1 lines on the divergent gather). One partial per block;
// separate reduce kernel (R3/R7: fence- and atomic-fusions both regressed).
// ---------------------------------------------------------------------------
__global__ __launch_bounds__(THREADS) void tersoff_main(
    const float4* __restrict__ pos4,
    const float* __restrict__ log_A,  const float* __restrict__ log_B,
    const float* __restrict__ log_l1, const float* __restrict__ log_l2,
    const float* __restrict__ log_l3, const float* __restrict__ log_beta,
    const float* __restrict__ log_n,  const float* __restrict__ log_gamma,
    const float* __restrict__ log_c,  const float* __restrict__ log_d,
    const float* __restrict__ E_ref,  const float* __restrict__ h_vals,
    const float* __restrict__ R_cut,  const float* __restrict__ D_wid,
    const int*  __restrict__ edge_dst,
    const int*  __restrict__ imap,
    float* __restrict__ partials, int nAtoms, int nTiles)
{
    __shared__ float PT[3][16];
    __shared__ int   IM[4];
    __shared__ float ER[2];
    // [node][slot][3 float4]; slot dim padded to 17 -> node stride 51 float4:
    // the 4 node-groups of a wave hit disjoint bank quads; within a group all
    // lanes read the same slot (broadcast, conflict-free).
    __shared__ float4 ED[NPB][DEG + 1][3];
    __shared__ float WS[THREADS / 64];

    if (threadIdx.x < 3) {
        int t = threadIdx.x;
        float A  = expf(log_A[t]);   float B  = expf(log_B[t]);
        float l1 = expf(log_l1[t]);  float l2 = expf(log_l2[t]);
        float l3 = expf(log_l3[t]);  float be = expf(log_beta[t]);
        float nn = expf(log_n[t]);   float ga = expf(log_gamma[t]);
        float c  = expf(log_c[t]);   float d  = expf(log_d[t]);
        float c2 = c * c, d2 = d * d;
        float R  = R_cut[t], D = D_wid[t];
        PT[t][0] = A;   PT[t][1] = B;
        PT[t][2] = l1;  PT[t][3] = l2;
        PT[t][4] = l3;  PT[t][5] = be;
        PT[t][6] = nn;  PT[t][7] = -1.0f / (2.0f * nn);
        PT[t][8] = h_vals[t];
        PT[t][9] = ga * (1.0f + c2 / d2);   // g1
        PT[t][10] = ga * c2;                // gc2
        PT[t][11] = d2;
        PT[t][12] = R - D;
        PT[t][13] = R + D;
        PT[t][14] = (float)M_PI / (2.0f * D);
    }
    if (threadIdx.x >= 64 && threadIdx.x < 68) IM[threadIdx.x - 64] = imap[threadIdx.x - 64];
    if (threadIdx.x >= 68 && threadIdx.x < 70) ER[threadIdx.x - 68] = E_ref[threadIdx.x - 68];
    __syncthreads();

    int nl   = threadIdx.x >> 4;          // node slot in tile (wave-local)
    int e    = threadIdx.x & (DEG - 1);   // edge slot within node
    int lane = threadIdx.x & 63;

    // ---- prefetch BOTH tiles' global data up front ----
    int t0 = blockIdx.x;
    int t1 = blockIdx.x + gridDim.x;
    int node0 = t0 * NPB + nl;  bool v0 = (node0 < nAtoms);  int nc0 = v0 ? node0 : 0;
    int node1 = t1 * NPB + nl;  bool v1 = (node1 < nAtoms);  int nc1 = v1 ? node1 : 0;
    int dst0 = edge_dst[nc0 * DEG + e];
    int dst1 = edge_dst[nc1 * DEG + e];
    float4 P00 = pos4[nc0];   float4 P10 = pos4[dst0];
    float4 P01 = pos4[nc1];   float4 P11 = pos4[dst1];

    float acc = 0.0f;

#define PROCESS_TILE(P0v, P1v, validv)                                         \
    {                                                                          \
        int ti = __float_as_int(P0v.w);                                        \
        int tj = __float_as_int(P1v.w);                                        \
        int p  = IM[ti * 2 + tj];                                              \
        float vx = P1v.x - P0v.x, vy = P1v.y - P0v.y, vz = P1v.z - P0v.z;      \
        float r2 = vx * vx + vy * vy + vz * vz;                                \
        float inv_r = __builtin_amdgcn_rsqf(r2);                               \
        float r = r2 * inv_r;                                                  \
        float RmD = PT[p][12], RpD = PT[p][13], piD = PT[p][14];               \
        float fc;                                                              \
        if (r < RmD)      fc = 1.0f;                                           \
        else if (r < RpD) fc = 0.5f - 0.5f * __sinf(piD * (r - RmD));          \
        else              fc = 0.0f;                                           \
        if (!(validv)) fc = 0.0f;                                              \
        float h  = PT[p][8], g1 = PT[p][9], gc2 = PT[p][10], d2 = PT[p][11];   \
        float ux = vx * inv_r, uy = vy * inv_r, uz = vz * inv_r;               \
        unsigned long long bal = __ballot(fc > 0.0f);                          \
        unsigned gm  = (unsigned)((bal >> (lane & 48)) & 0xFFFFull);           \
        int nact = __popc(gm);                                                 \
        int rank = __popc(gm & ((1u << (lane & 15)) - 1u));                    \
        if (fc > 0.0f) {                                                       \
            ED[nl][rank][0] = make_float4(ux, uy, uz, r);                      \
            ED[nl][rank][1] = make_float4(fc, PT[p][4], h, g1);                \
            ED[nl][rank][2] = make_float4(gc2, d2, 0.0f, 0.0f);                \
        }                                                                      \
        if ((validv) && e == 0) acc += ti ? ER[1] : ER[0];                     \
        __syncthreads();                                                       \
        if (fc > 0.0f) {                                                       \
            float zeta = 0.0f;                                                 \
            for (int s = 0; s < nact; ++s) {                                   \
                if (s == rank) continue;                                       \
                float4 fa = ED[nl][s][0];                                      \
                float4 fb = ED[nl][s][1];                                      \
                float4 fx = ED[nl][s][2];                                      \
                float ct = ux * fa.x + uy * fa.y + uz * fa.z;                  \
                ct = fminf(fmaxf(ct, -1.0f), 1.0f);                            \
                bool mine = (s < rank);                                        \
                float hh  = mine ? h   : fb.z;                                 \
                float G1  = mine ? g1  : fb.w;                                 \
                float GC2 = mine ? gc2 : fx.x;                                 \
                float D2  = mine ? d2  : fx.y;                                 \
                float hm  = hh - ct;                                           \
                float ang = G1 - GC2 * __builtin_amdgcn_rcpf(D2 + hm * hm);    \
                float ex  = __expf(fminf(fb.y * (r - fa.w), 35.0f));           \
                zeta += fb.x * ang * ex;                                       \
            }                                                                  \
            float be  = PT[p][5], nn = PT[p][6], m2n = PT[p][7];               \
            float xx  = __powf(be * zeta, nn);                                 \
            float bo  = __powf(1.0f + xx, m2n);                                \
            float rep =  PT[p][0] * __expf(-PT[p][2] * r);                     \
            float att = -PT[p][1] * __expf(-PT[p][3] * r);                     \
            acc += 0.5f * fc * (rep + bo * att);                               \
        }                                                                      \
        __syncthreads();                                                       \
    }

    PROCESS_TILE(P00, P10, v0)
    PROCESS_TILE(P01, P11, v1)
#undef PROCESS_TILE

    // once per block: wave reduce, cross-wave via LDS
    for (int o = 32; o > 0; o >>= 1) acc += __shfl_down(acc, o, 64);
    if ((threadIdx.x & 63) == 0) WS[threadIdx.x >> 6] = acc;
    __syncthreads();
    if (threadIdx.x == 0) {
        float s = 0.0f;
        #pragma unroll
        for (int w = 0; w < THREADS / 64; ++w) s += WS[w];
        partials[blockIdx.x] = s;
    }
}

__global__ __launch_bounds__(256) void reduce_kernel(
    const float* __restrict__ in, int n, float* __restrict__ out)
{
    float acc = 0.0f;
    for (int i = threadIdx.x; i < n; i += 256) acc += in[i];
    for (int o = 32; o > 0; o >>= 1) acc += __shfl_down(acc, o, 64);
    __shared__ float WS[4];
    if ((threadIdx.x & 63) == 0) WS[threadIdx.x >> 6] = acc;
    __syncthreads();
    if (threadIdx.x == 0) out[0] = WS[0] + WS[1] + WS[2] + WS[3];
}

extern "C" void kernel_launch(void* const* d_in, const int* in_sizes, int n_in,
                              void* d_out, int out_size, void* d_ws, size_t ws_size,
                              hipStream_t stream) {
    const float* pos      = (const float*)d_in[0];
    const float* log_A    = (const float*)d_in[1];
    const float* log_B    = (const float*)d_in[2];
    const float* log_l1   = (const float*)d_in[3];
    const float* log_l2   = (const float*)d_in[4];
    const float* log_l3   = (const float*)d_in[5];
    const float* log_beta = (const float*)d_in[6];
    const float* log_n    = (const float*)d_in[7];
    const float* log_gam  = (const float*)d_in[8];
    const float* log_c    = (const float*)d_in[9];
    const float* log_d    = (const float*)d_in[10];
    const float* E_ref    = (const float*)d_in[11];
    const float* h_vals   = (const float*)d_in[12];
    const float* R_cut    = (const float*)d_in[13];
    const float* D_wid    = (const float*)d_in[14];
    const int*   edge_idx = (const int*)d_in[15];
    // d_in[16] trip_ij, d_in[17] trip_ik: implicit (triu pairs per node) -- unused.
    const int*   atypes   = (const int*)d_in[18];
    const int*   imap     = (const int*)d_in[19];
    // d_in[20] batch: all zeros -- unused.

    int nAtoms = in_sizes[0] / 3;
    int E      = in_sizes[15] / 2;
    const int* edge_dst = edge_idx + E;

    int nTiles = (nAtoms + NPB - 1) / NPB;       // 3125
    int grid   = (nTiles + 1) / 2;               // 1563 (2 tiles per block)

    // d_ws layout: partials | pos4 (256-aligned)
    char* ws = (char*)d_ws;
    size_t pos4_off = ((size_t)grid * 4 + 255) & ~(size_t)255;
    float*  partials = (float*)ws;
    float4* pos4     = (float4*)(ws + pos4_off);

    int pblk = (nAtoms + 255) / 256;
    pack_kernel<<<pblk, 256, 0, stream>>>(pos, atypes, pos4, nAtoms);
    tersoff_main<<<grid, THREADS, 0, stream>>>(
        pos4, log_A, log_B, log_l1, log_l2, log_l3, log_beta, log_n,
        log_gam, log_c, log_d, E_ref, h_vals, R_cut, D_wid,
        edge_dst, imap, partials, nAtoms, nTiles);
    reduce_kernel<<<1, 256, 0, stream>>>(partials, grid, (float*)d_out);
}

// Round 9
// 24.680 us; speedup vs baseline: 1.5152x; 1.2642x over previous
//
#include <hip/hip_runtime.h>
#include <math.h>
#include <string.h>

#ifndef M_PI
#define M_PI 3.14159265358979323846
#endif

#define DEG 16
#define NPB 16                  // nodes per tile
#define THREADS (DEG * NPB)     // 256
#define TILES_PER_BLOCK 2

// R5 structure (best: 25.7us) + one dwordx4 pos gather (3 divergent loads -> 1)
// + EXACT specialization (N % 16 == 0 drops all valid-predication).
// Lessons kept: no pack kernel (R4/R8), no upfront cross-tile prefetch (R8),
// no fused reduction via fence or atomic (R3/R7), keep per-tile barriers
// (R6/R7: removing them regressed).
template <bool EXACT>
__global__ __launch_bounds__(THREADS) void tersoff_main(
    const float* __restrict__ pos,
    const float* __restrict__ log_A,  const float* __restrict__ log_B,
    const float* __restrict__ log_l1, const float* __restrict__ log_l2,
    const float* __restrict__ log_l3, const float* __restrict__ log_beta,
    const float* __restrict__ log_n,  const float* __restrict__ log_gamma,
    const float* __restrict__ log_c,  const float* __restrict__ log_d,
    const float* __restrict__ E_ref,  const float* __restrict__ h_vals,
    const float* __restrict__ R_cut,  const float* __restrict__ D_wid,
    const int*  __restrict__ edge_dst,
    const int*  __restrict__ atom_types,
    const int*  __restrict__ imap,
    float* __restrict__ partials, int nAtoms, int nTiles)
{
    __shared__ float PT[3][16];
    __shared__ int   IM[4];
    __shared__ float ER[2];
    // [node][slot][3 float4]; slot dim padded to 17 -> node stride 51 float4:
    // the 4 node-groups of a wave hit disjoint bank quads; within a group all
    // lanes read the same slot (broadcast, conflict-free).
    __shared__ float4 ED[NPB][DEG + 1][3];
    __shared__ float WS[THREADS / 64];

    if (threadIdx.x < 3) {
        int t = threadIdx.x;
        float A  = expf(log_A[t]);   float B  = expf(log_B[t]);
        float l1 = expf(log_l1[t]);  float l2 = expf(log_l2[t]);
        float l3 = expf(log_l3[t]);  float be = expf(log_beta[t]);
        float nn = expf(log_n[t]);   float ga = expf(log_gamma[t]);
        float c  = expf(log_c[t]);   float d  = expf(log_d[t]);
        float c2 = c * c, d2 = d * d;
        float R  = R_cut[t], D = D_wid[t];
        PT[t][0] = A;   PT[t][1] = B;
        PT[t][2] = l1;  PT[t][3] = l2;
        PT[t][4] = l3;  PT[t][5] = be;
        PT[t][6] = nn;  PT[t][7] = -1.0f / (2.0f * nn);
        PT[t][8] = h_vals[t];
        PT[t][9] = ga * (1.0f + c2 / d2);   // g1
        PT[t][10] = ga * c2;                // gc2
        PT[t][11] = d2;
        PT[t][12] = R - D;
        PT[t][13] = R + D;
        PT[t][14] = (float)M_PI / (2.0f * D);
    }
    if (threadIdx.x >= 64 && threadIdx.x < 68) IM[threadIdx.x - 64] = imap[threadIdx.x - 64];
    if (threadIdx.x >= 68 && threadIdx.x < 70) ER[threadIdx.x - 68] = E_ref[threadIdx.x - 68];
    __syncthreads();

    int nl   = threadIdx.x >> 4;          // node slot in tile (wave-local)
    int e    = threadIdx.x & (DEG - 1);   // edge slot within node
    int lane = threadIdx.x & 63;

    float acc = 0.0f;
    int last3 = 3 * nAtoms - 4;           // clamp base for the dst==N-1 dwordx4

    for (int tile = blockIdx.x; tile < nTiles; tile += gridDim.x) {
        int node = tile * NPB + nl;
        bool valid = EXACT ? true : (node < nAtoms);
        int nc = EXACT ? node : (valid ? node : 0);

        int dst = edge_dst[nc * DEG + e];
        int ti  = atom_types[nc];
        int tj  = atom_types[dst];
        int p   = IM[ti * 2 + tj];

        // --- neighbor position: ONE global_load_dwordx4 (align 4) ---
        int b3 = 3 * dst;
        int dd = (b3 > last3) ? 1 : 0;    // only dst == nAtoms-1
        float4 pv;
        __builtin_memcpy(&pv, pos + (b3 - dd), 16);
        float qx = dd ? pv.y : pv.x;
        float qy = dd ? pv.z : pv.y;
        float qz = dd ? pv.w : pv.z;
        // own node (group-uniform -> TA-cheap): same trick, 1 instr
        int c3 = 3 * nc;
        int d0 = (c3 > last3) ? 1 : 0;
        float4 pu;
        __builtin_memcpy(&pu, pos + (c3 - d0), 16);
        float px = d0 ? pu.y : pu.x;
        float py = d0 ? pu.z : pu.y;
        float pz = d0 ? pu.w : pu.z;

        float vx = qx - px, vy = qy - py, vz = qz - pz;
        float r2 = vx * vx + vy * vy + vz * vz;
        float inv_r = __builtin_amdgcn_rsqf(r2);
        float r = r2 * inv_r;

        float RmD = PT[p][12], RpD = PT[p][13], piD = PT[p][14];
        float fc;
        if (r < RmD)      fc = 1.0f;
        else if (r < RpD) fc = 0.5f - 0.5f * __sinf(piD * (r - RmD));
        else              fc = 0.0f;
        if (!EXACT && !valid) fc = 0.0f;

        float h  = PT[p][8], g1 = PT[p][9], gc2 = PT[p][10], d2 = PT[p][11];
        float ux = vx * inv_r, uy = vy * inv_r, uz = vz * inv_r;

        // order-preserving per-16-group compaction of active edges
        unsigned long long bal = __ballot(fc > 0.0f);
        unsigned gm  = (unsigned)((bal >> (lane & 48)) & 0xFFFFull);
        int nact = __popc(gm);
        int rank = __popc(gm & ((1u << (lane & 15)) - 1u));
        if (fc > 0.0f) {
            ED[nl][rank][0] = make_float4(ux, uy, uz, r);
            ED[nl][rank][1] = make_float4(fc, PT[p][4], h, g1);
            ED[nl][rank][2] = make_float4(gc2, d2, 0.0f, 0.0f);
        }
        if ((EXACT || valid) && e == 0) acc += ti ? ER[1] : ER[0];
        __syncthreads();

        if (fc > 0.0f) {
            float zeta = 0.0f;
            for (int s = 0; s < nact; ++s) {
                if (s == rank) continue;       // skip self
                float4 fa = ED[nl][s][0];      // {ux, uy, uz, r}
                float4 fb = ED[nl][s][1];      // {fc, lam3, h, g1}
                float4 fx = ED[nl][s][2];      // {gc2, d2, -, -}
                float ct = ux * fa.x + uy * fa.y + uz * fa.z;
                ct = fminf(fmaxf(ct, -1.0f), 1.0f);
                bool mine = (s < rank);        // ang params from larger-index edge
                float hh  = mine ? h   : fb.z;
                float G1  = mine ? g1  : fb.w;
                float GC2 = mine ? gc2 : fx.x;
                float D2  = mine ? d2  : fx.y;
                float hm  = hh - ct;
                float ang = G1 - GC2 * __builtin_amdgcn_rcpf(D2 + hm * hm);
                float ex  = __expf(fminf(fb.y * (r - fa.w), 35.0f));
                zeta += fb.x * ang * ex;
            }
            float be  = PT[p][5], nn = PT[p][6], m2n = PT[p][7];
            float xx  = __powf(be * zeta, nn);     // (beta*zeta)^n
            float bo  = __powf(1.0f + xx, m2n);    // (1+x)^(-1/(2n))
            float rep =  PT[p][0] * __expf(-PT[p][2] * r);
            float att = -PT[p][1] * __expf(-PT[p][3] * r);
            acc += 0.5f * fc * (rep + bo * att);
        }
        __syncthreads();   // WAR: protect ED before next tile's writes
    }

    // once per block: wave reduce, cross-wave via LDS
    for (int o = 32; o > 0; o >>= 1) acc += __shfl_down(acc, o, 64);
    if ((threadIdx.x & 63) == 0) WS[threadIdx.x >> 6] = acc;
    __syncthreads();
    if (threadIdx.x == 0) {
        float s = 0.0f;
        #pragma unroll
        for (int w = 0; w < THREADS / 64; ++w) s += WS[w];
        partials[blockIdx.x] = s;
    }
}

__global__ __launch_bounds__(256) void reduce_kernel(
    const float* __restrict__ in, int n, float* __restrict__ out)
{
    float acc = 0.0f;
    for (int i = threadIdx.x; i < n; i += 256) acc += in[i];
    for (int o = 32; o > 0; o >>= 1) acc += __shfl_down(acc, o, 64);
    __shared__ float WS[4];
    if ((threadIdx.x & 63) == 0) WS[threadIdx.x >> 6] = acc;
    __syncthreads();
    if (threadIdx.x == 0) out[0] = WS[0] + WS[1] + WS[2] + WS[3];
}

extern "C" void kernel_launch(void* const* d_in, const int* in_sizes, int n_in,
                              void* d_out, int out_size, void* d_ws, size_t ws_size,
                              hipStream_t stream) {
    const float* pos      = (const float*)d_in[0];
    const float* log_A    = (const float*)d_in[1];
    const float* log_B    = (const float*)d_in[2];
    const float* log_l1   = (const float*)d_in[3];
    const float* log_l2   = (const float*)d_in[4];
    const float* log_l3   = (const float*)d_in[5];
    const float* log_beta = (const float*)d_in[6];
    const float* log_n    = (const float*)d_in[7];
    const float* log_gam  = (const float*)d_in[8];
    const float* log_c    = (const float*)d_in[9];
    const float* log_d    = (const float*)d_in[10];
    const float* E_ref    = (const float*)d_in[11];
    const float* h_vals   = (const float*)d_in[12];
    const float* R_cut    = (const float*)d_in[13];
    const float* D_wid    = (const float*)d_in[14];
    const int*   edge_idx = (const int*)d_in[15];
    // d_in[16] trip_ij, d_in[17] trip_ik: implicit (triu pairs per node) -- unused.
    const int*   atypes   = (const int*)d_in[18];
    const int*   imap     = (const int*)d_in[19];
    // d_in[20] batch: all zeros -- unused.

    int nAtoms = in_sizes[0] / 3;
    int E      = in_sizes[15] / 2;
    const int* edge_dst = edge_idx + E;

    int nTiles = (nAtoms + NPB - 1) / NPB;                          // 3125
    int grid   = (nTiles + TILES_PER_BLOCK - 1) / TILES_PER_BLOCK;  // 1563

    float* partials = (float*)d_ws;

    if (nTiles * NPB == nAtoms) {
        tersoff_main<true><<<grid, THREADS, 0, stream>>>(
            pos, log_A, log_B, log_l1, log_l2, log_l3, log_beta, log_n,
            log_gam, log_c, log_d, E_ref, h_vals, R_cut, D_wid,
            edge_dst, atypes, imap, partials, nAtoms, nTiles);
    } else {
        tersoff_main<false><<<grid, THREADS, 0, stream>>>(
            pos, log_A, log_B, log_l1, log_l2, log_l3, log_beta, log_n,
            log_gam, log_c, log_d, E_ref, h_vals, R_cut, D_wid,
            edge_dst, atypes, imap, partials, nAtoms, nTiles);
    }
    reduce_kernel<<<1, 256, 0, stream>>>(partials, grid, (float*)d_out);
}

// Round 10
// 24.046 us; speedup vs baseline: 1.5552x; 1.0264x over previous
//
#include <hip/hip_runtime.h>
#include <math.h>
#include <string.h>

#ifndef M_PI
#define M_PI 3.14159265358979323846
#endif

#define DEG 16
#define NPB 16                  // nodes per tile
#define THREADS (DEG * NPB)     // 256
#define TILES_PER_BLOCK 2

// R9 (best: 24.7us) with the two per-tile __syncthreads removed. All ED
// sharing is within a 16-lane group (wave-internal); the DS pipe processes
// a wave's LDS ops in order, so RAW/WAR within the wave needs no barrier
// (empirically verified correct in R6/R7, absmax 0.0). Removing the barriers
// removes the compiler's vmcnt(0) drain per tile, letting tile k+1's load
// chain overlap tile k's zeta compute.
// Kept lessons: no pack kernel (R4/R8), no upfront cross-tile prefetch (R8),
// no fused reduction via fence/atomic/memset (R3/R7), 2-kernel structure.
template <bool EXACT>
__global__ __launch_bounds__(THREADS) void tersoff_main(
    const float* __restrict__ pos,
    const float* __restrict__ log_A,  const float* __restrict__ log_B,
    const float* __restrict__ log_l1, const float* __restrict__ log_l2,
    const float* __restrict__ log_l3, const float* __restrict__ log_beta,
    const float* __restrict__ log_n,  const float* __restrict__ log_gamma,
    const float* __restrict__ log_c,  const float* __restrict__ log_d,
    const float* __restrict__ E_ref,  const float* __restrict__ h_vals,
    const float* __restrict__ R_cut,  const float* __restrict__ D_wid,
    const int*  __restrict__ edge_dst,
    const int*  __restrict__ atom_types,
    const int*  __restrict__ imap,
    float* __restrict__ partials, int nAtoms, int nTiles)
{
    __shared__ float PT[3][16];
    __shared__ int   IM[4];
    __shared__ float ER[2];
    // [node][slot][3 float4]; slot dim padded to 17 -> node stride 51 float4:
    // the 4 node-groups of a wave hit disjoint bank quads; within a group all
    // lanes read the same slot (broadcast, conflict-free).
    __shared__ float4 ED[NPB][DEG + 1][3];
    __shared__ float WS[THREADS / 64];

    if (threadIdx.x < 3) {
        int t = threadIdx.x;
        float A  = expf(log_A[t]);   float B  = expf(log_B[t]);
        float l1 = expf(log_l1[t]);  float l2 = expf(log_l2[t]);
        float l3 = expf(log_l3[t]);  float be = expf(log_beta[t]);
        float nn = expf(log_n[t]);   float ga = expf(log_gamma[t]);
        float c  = expf(log_c[t]);   float d  = expf(log_d[t]);
        float c2 = c * c, d2 = d * d;
        float R  = R_cut[t], D = D_wid[t];
        PT[t][0] = A;   PT[t][1] = B;
        PT[t][2] = l1;  PT[t][3] = l2;
        PT[t][4] = l3;  PT[t][5] = be;
        PT[t][6] = nn;  PT[t][7] = -1.0f / (2.0f * nn);
        PT[t][8] = h_vals[t];
        PT[t][9] = ga * (1.0f + c2 / d2);   // g1
        PT[t][10] = ga * c2;                // gc2
        PT[t][11] = d2;
        PT[t][12] = R - D;
        PT[t][13] = R + D;
        PT[t][14] = (float)M_PI / (2.0f * D);
    }
    if (threadIdx.x >= 64 && threadIdx.x < 68) IM[threadIdx.x - 64] = imap[threadIdx.x - 64];
    if (threadIdx.x >= 68 && threadIdx.x < 70) ER[threadIdx.x - 68] = E_ref[threadIdx.x - 68];
    __syncthreads();    // PT/IM/ER are cross-wave: this barrier stays

    int nl   = threadIdx.x >> 4;          // node slot in tile (wave-local)
    int e    = threadIdx.x & (DEG - 1);   // edge slot within node
    int lane = threadIdx.x & 63;

    float acc = 0.0f;
    int last3 = 3 * nAtoms - 4;           // clamp base for the dst==N-1 dwordx4

    for (int tile = blockIdx.x; tile < nTiles; tile += gridDim.x) {
        int node = tile * NPB + nl;
        bool valid = EXACT ? true : (node < nAtoms);
        int nc = EXACT ? node : (valid ? node : 0);

        int dst = edge_dst[nc * DEG + e];
        int ti  = atom_types[nc];
        int tj  = atom_types[dst];
        int p   = IM[ti * 2 + tj];

        // --- neighbor position: ONE global_load_dwordx4 (align 4) ---
        int b3 = 3 * dst;
        int dd = (b3 > last3) ? 1 : 0;    // only dst == nAtoms-1
        float4 pv;
        __builtin_memcpy(&pv, pos + (b3 - dd), 16);
        float qx = dd ? pv.y : pv.x;
        float qy = dd ? pv.z : pv.y;
        float qz = dd ? pv.w : pv.z;
        // own node (group-uniform -> TA-cheap): same trick, 1 instr
        int c3 = 3 * nc;
        int d0 = (c3 > last3) ? 1 : 0;
        float4 pu;
        __builtin_memcpy(&pu, pos + (c3 - d0), 16);
        float px = d0 ? pu.y : pu.x;
        float py = d0 ? pu.z : pu.y;
        float pz = d0 ? pu.w : pu.z;

        float vx = qx - px, vy = qy - py, vz = qz - pz;
        float r2 = vx * vx + vy * vy + vz * vz;
        float inv_r = __builtin_amdgcn_rsqf(r2);
        float r = r2 * inv_r;

        float RmD = PT[p][12], RpD = PT[p][13], piD = PT[p][14];
        float fc;
        if (r < RmD)      fc = 1.0f;
        else if (r < RpD) fc = 0.5f - 0.5f * __sinf(piD * (r - RmD));
        else              fc = 0.0f;
        if (!EXACT && !valid) fc = 0.0f;

        float h  = PT[p][8], g1 = PT[p][9], gc2 = PT[p][10], d2 = PT[p][11];
        float ux = vx * inv_r, uy = vy * inv_r, uz = vz * inv_r;

        // order-preserving per-16-group compaction of active edges
        unsigned long long bal = __ballot(fc > 0.0f);
        unsigned gm  = (unsigned)((bal >> (lane & 48)) & 0xFFFFull);
        int nact = __popc(gm);
        int rank = __popc(gm & ((1u << (lane & 15)) - 1u));
        if (fc > 0.0f) {
            ED[nl][rank][0] = make_float4(ux, uy, uz, r);
            ED[nl][rank][1] = make_float4(fc, PT[p][4], h, g1);
            ED[nl][rank][2] = make_float4(gc2, d2, 0.0f, 0.0f);
        }
        if ((EXACT || valid) && e == 0) acc += ti ? ER[1] : ER[0];
        // no barrier: ED producer/consumer lanes are in the SAME wave; the
        // DS pipe processes a wave's LDS ops in order (verified R6/R7).

        if (fc > 0.0f) {
            float zeta = 0.0f;
            for (int s = 0; s < nact; ++s) {
                if (s == rank) continue;       // skip self
                float4 fa = ED[nl][s][0];      // {ux, uy, uz, r}
                float4 fb = ED[nl][s][1];      // {fc, lam3, h, g1}
                float4 fx = ED[nl][s][2];      // {gc2, d2, -, -}
                float ct = ux * fa.x + uy * fa.y + uz * fa.z;
                ct = fminf(fmaxf(ct, -1.0f), 1.0f);
                bool mine = (s < rank);        // ang params from larger-index edge
                float hh  = mine ? h   : fb.z;
                float G1  = mine ? g1  : fb.w;
                float GC2 = mine ? gc2 : fx.x;
                float D2  = mine ? d2  : fx.y;
                float hm  = hh - ct;
                float ang = G1 - GC2 * __builtin_amdgcn_rcpf(D2 + hm * hm);
                float ex  = __expf(fminf(fb.y * (r - fa.w), 35.0f));
                zeta += fb.x * ang * ex;
            }
            float be  = PT[p][5], nn = PT[p][6], m2n = PT[p][7];
            float xx  = __powf(be * zeta, nn);     // (beta*zeta)^n
            float bo  = __powf(1.0f + xx, m2n);    // (1+x)^(-1/(2n))
            float rep =  PT[p][0] * __expf(-PT[p][2] * r);
            float att = -PT[p][1] * __expf(-PT[p][3] * r);
            acc += 0.5f * fc * (rep + bo * att);
        }
        // no barrier: WAR on ED is wave-internal (in-order DS pipe)
    }

    // once per block: wave reduce, cross-wave via LDS
    for (int o = 32; o > 0; o >>= 1) acc += __shfl_down(acc, o, 64);
    if ((threadIdx.x & 63) == 0) WS[threadIdx.x >> 6] = acc;
    __syncthreads();    // cross-wave WS handoff: this barrier stays
    if (threadIdx.x == 0) {
        float s = 0.0f;
        #pragma unroll
        for (int w = 0; w < THREADS / 64; ++w) s += WS[w];
        partials[blockIdx.x] = s;
    }
}

__global__ __launch_bounds__(256) void reduce_kernel(
    const float* __restrict__ in, int n, float* __restrict__ out)
{
    float acc = 0.0f;
    for (int i = threadIdx.x; i < n; i += 256) acc += in[i];
    for (int o = 32; o > 0; o >>= 1) acc += __shfl_down(acc, o, 64);
    __shared__ float WS[4];
    if ((threadIdx.x & 63) == 0) WS[threadIdx.x >> 6] = acc;
    __syncthreads();
    if (threadIdx.x == 0) out[0] = WS[0] + WS[1] + WS[2] + WS[3];
}

extern "C" void kernel_launch(void* const* d_in, const int* in_sizes, int n_in,
                              void* d_out, int out_size, void* d_ws, size_t ws_size,
                              hipStream_t stream) {
    const float* pos      = (const float*)d_in[0];
    const float* log_A    = (const float*)d_in[1];
    const float* log_B    = (const float*)d_in[2];
    const float* log_l1   = (const float*)d_in[3];
    const float* log_l2   = (const float*)d_in[4];
    const float* log_l3   = (const float*)d_in[5];
    const float* log_beta = (const float*)d_in[6];
    const float* log_n    = (const float*)d_in[7];
    const float* log_gam  = (const float*)d_in[8];
    const float* log_c    = (const float*)d_in[9];
    const float* log_d    = (const float*)d_in[10];
    const float* E_ref    = (const float*)d_in[11];
    const float* h_vals   = (const float*)d_in[12];
    const float* R_cut    = (const float*)d_in[13];
    const float* D_wid    = (const float*)d_in[14];
    const int*   edge_idx = (const int*)d_in[15];
    // d_in[16] trip_ij, d_in[17] trip_ik: implicit (triu pairs per node) -- unused.
    const int*   atypes   = (const int*)d_in[18];
    const int*   imap     = (const int*)d_in[19];
    // d_in[20] batch: all zeros -- unused.

    int nAtoms = in_sizes[0] / 3;
    int E      = in_sizes[15] / 2;
    const int* edge_dst = edge_idx + E;

    int nTiles = (nAtoms + NPB - 1) / NPB;                          // 3125
    int grid   = (nTiles + TILES_PER_BLOCK - 1) / TILES_PER_BLOCK;  // 1563

    float* partials = (float*)d_ws;

    if (nTiles * NPB == nAtoms) {
        tersoff_main<true><<<grid, THREADS, 0, stream>>>(
            pos, log_A, log_B, log_l1, log_l2, log_l3, log_beta, log_n,
            log_gam, log_c, log_d, E_ref, h_vals, R_cut, D_wid,
            edge_dst, atypes, imap, partials, nAtoms, nTiles);
    } else {
        tersoff_main<false><<<grid, THREADS, 0, stream>>>(
            pos, log_A, log_B, log_l1, log_l2, log_l3, log_beta, log_n,
            log_gam, log_c, log_d, E_ref, h_vals, R_cut, D_wid,
            edge_dst, atypes, imap, partials, nAtoms, nTiles);
    }
    reduce_kernel<<<1, 256, 0, stream>>>(partials, grid, (float*)d_out);
}